// Round 9
// baseline (3001.803 us; speedup 1.0000x reference)
//
#include <hip/hip_runtime.h>
#include <math.h>

#define BB 128
#define NN 2048
#define CMID 64
#define HH 128
#define G4 512
#define NCLS 40
#define CH 32
#define NCH (NN / CH)
#define EPSV 1e-5f
#define HPAD 36

__device__ __forceinline__ float fsigmoid(float x) {
    return 1.0f / (1.0f + __expf(-x));
}
__device__ __forceinline__ float ftanh2(float x) {
    return 2.0f / (1.0f + __expf(-2.0f * x)) - 1.0f;
}
__device__ __forceinline__ void fma4(float& a, const float4 w, const float4 v) {
    a = fmaf(w.x, v.x, a);
    a = fmaf(w.y, v.y, a);
    a = fmaf(w.z, v.z, a);
    a = fmaf(w.w, v.w, a);
}
// gfx950: VALU cannot source AGPRs directly (R8 compile error), but
// v_accvgpr_read/write work.  Weights parked in AGPRs are un-rematerializable
// and cost 1 VALU read per use -- far cheaper than any memory-path refetch.
__device__ __forceinline__ void awrite(float& a, float v) {
    asm volatile("v_accvgpr_write_b32 %0, %1" : "=a"(a) : "v"(v));
}
__device__ __forceinline__ float aread(const float& a) {
    float v;
    asm volatile("v_accvgpr_read_b32 %0, %1" : "=v"(v) : "a"(a));
    return v;
}

// 512 threads, 1 block per batch element.
// Per 32-step chunk: conv+BN+ReLU -> hcT; GEMM xg = bias + W_ih*hc -> LDS
// (parallel phases); serial recurrence needs only W_hh: thread = (unit
// j=t>>2, slice s=t&3 over 32 h-dims), gates {i,f} weights in VGPRs (64),
// gates {g,o} weights in AGPRs (64, accvgpr_read per use).  Total resident
// VGPR ~110 <= the backend's hard 128 cap (= 65536/threads, rounds 2/5/6/7).
__global__ __attribute__((amdgpu_flat_work_group_size(512, 512),
                          amdgpu_waves_per_eu(2, 2)))
void lstm_seq_kernel(const float* __restrict__ x,
                     const float* __restrict__ conv_w, const float* __restrict__ conv_b,
                     const float* __restrict__ gamma,  const float* __restrict__ beta,
                     const float* __restrict__ rmean,  const float* __restrict__ rvar,
                     const float* __restrict__ W_ih,   const float* __restrict__ W_hh,
                     const float* __restrict__ b_ih,   const float* __restrict__ b_hh,
                     const float* __restrict__ W_out,  const float* __restrict__ b_out,
                     float* __restrict__ out)
{
    __shared__ float xg_s[CH][4][HH];    // 64 KB: gate pre-activations [n][gate][unit]
    __shared__ float hcT[CMID][HPAD];    // 9 KB:  hc transposed, padded rows
    __shared__ float h_p[2][4][HPAD];    // 1.1 KB: hidden, slice-padded + dbuf
    __shared__ float cf_s[4][CMID];      // folded conv+BN coeffs
    __shared__ float bias_s[G4];         // b_ih + b_hh

    const int t = threadIdx.x;
    const int b = blockIdx.x;
    const int j = t >> 2;    // unit 0..127
    const int s = t & 3;     // h-slice 0..3 (32 dims)

    if (t < CMID) {
        float inv = gamma[t] * rsqrtf(rvar[t] + EPSV);
        cf_s[0][t] = conv_w[t * 3 + 0] * inv;
        cf_s[1][t] = conv_w[t * 3 + 1] * inv;
        cf_s[2][t] = conv_w[t * 3 + 2] * inv;
        cf_s[3][t] = (conv_b[t] - rmean[t]) * inv + beta[t];
    }
    bias_s[t] = b_ih[t] + b_hh[t];
    if (t < 2 * 4 * HPAD) ((float*)h_p)[t] = 0.0f;

    // ---- serial-phase W_hh: gates i,f in VGPR; gates g,o in AGPR ----
    float4 whh_v[2][8];
    #pragma unroll
    for (int i = 0; i < 8; ++i) {
        whh_v[0][i] = *(const float4*)(W_hh + (size_t)(0 * HH + j) * HH + s * 32 + 4 * i);
        whh_v[1][i] = *(const float4*)(W_hh + (size_t)(1 * HH + j) * HH + s * 32 + 4 * i);
    }
    float wa_g[32], wa_o[32];
    #pragma unroll
    for (int i = 0; i < 8; ++i) {
        float4 wg = *(const float4*)(W_hh + (size_t)(2 * HH + j) * HH + s * 32 + 4 * i);
        float4 wo = *(const float4*)(W_hh + (size_t)(3 * HH + j) * HH + s * 32 + 4 * i);
        awrite(wa_g[4 * i + 0], wg.x); awrite(wa_g[4 * i + 1], wg.y);
        awrite(wa_g[4 * i + 2], wg.z); awrite(wa_g[4 * i + 3], wg.w);
        awrite(wa_o[4 * i + 0], wo.x); awrite(wa_o[4 * i + 1], wo.y);
        awrite(wa_o[4 * i + 2], wo.z); awrite(wa_o[4 * i + 3], wo.w);
    }

    float c_reg = 0.0f;
    const float* xb = x + (size_t)b * NN * 3;

    for (int ch = 0; ch < NCH; ++ch) {
        const int base = ch * CH;
        __syncthreads();   // init visible (iter 0); otherwise spacing only

        // ---- phase-0: conv+BN+ReLU -> hcT[c][n] ----
        {
            const int c  = t & 63;
            const int nb = t >> 6;           // 0..7, 4 timesteps each
            const float A0 = cf_s[0][c], A1 = cf_s[1][c];
            const float A2 = cf_s[2][c], D0 = cf_s[3][c];
            float4 hv;
            #pragma unroll
            for (int i = 0; i < 4; ++i) {
                const int n = nb * 4 + i;
                const float* xp = xb + (size_t)(base + n) * 3;
                float r = D0 + A0 * xp[0] + A1 * xp[1] + A2 * xp[2];
                ((float*)&hv)[i] = fmaxf(r, 0.0f);
            }
            *(float4*)&hcT[c][nb * 4] = hv;
        }
        __syncthreads();

        // ---- phase-1: xg[n][q][j] = bias + W_ih[row]·hc[n]  (row = t) ----
        {
            const int q  = t >> 7;
            const int jj = t & 127;
            float acc[CH];
            const float bv = bias_s[t];
            #pragma unroll
            for (int n = 0; n < CH; ++n) acc[n] = bv;
            const float* wp = W_ih + (size_t)t * CMID;
            for (int k4 = 0; k4 < 16; ++k4) {
                float4 w4 = *(const float4*)(wp + 4 * k4);
                #pragma unroll
                for (int e = 0; e < 4; ++e) {
                    const int k = 4 * k4 + e;
                    const float wv = ((const float*)&w4)[e];
                    const float4* hr = (const float4*)&hcT[k][0];
                    #pragma unroll
                    for (int n4 = 0; n4 < 8; ++n4) {
                        float4 hv = hr[n4];
                        acc[n4 * 4 + 0] = fmaf(wv, hv.x, acc[n4 * 4 + 0]);
                        acc[n4 * 4 + 1] = fmaf(wv, hv.y, acc[n4 * 4 + 1]);
                        acc[n4 * 4 + 2] = fmaf(wv, hv.z, acc[n4 * 4 + 2]);
                        acc[n4 * 4 + 3] = fmaf(wv, hv.w, acc[n4 * 4 + 3]);
                    }
                }
            }
            #pragma unroll
            for (int n = 0; n < CH; ++n) xg_s[n][q][jj] = acc[n];
        }
        __syncthreads();

        // ---- phase-2: serial recurrence, one barrier per step ----
        for (int k = 0; k < CH; ++k) {
            const int p = k & 1;            // CH even -> global parity = k&1
            float a0 = 0.f, a1 = 0.f, a2 = 0.f, a3 = 0.f;
            const float4* hp = (const float4*)&h_p[p][s][0];
            #pragma unroll
            for (int i = 0; i < 8; ++i) {
                float4 hv = hp[i];
                fma4(a0, whh_v[0][i], hv);
                fma4(a1, whh_v[1][i], hv);
                float t0, t1;
                t0 = aread(wa_g[4 * i + 0]); t1 = aread(wa_o[4 * i + 0]);
                a2 = fmaf(t0, hv.x, a2);     a3 = fmaf(t1, hv.x, a3);
                t0 = aread(wa_g[4 * i + 1]); t1 = aread(wa_o[4 * i + 1]);
                a2 = fmaf(t0, hv.y, a2);     a3 = fmaf(t1, hv.y, a3);
                t0 = aread(wa_g[4 * i + 2]); t1 = aread(wa_o[4 * i + 2]);
                a2 = fmaf(t0, hv.z, a2);     a3 = fmaf(t1, hv.z, a3);
                t0 = aread(wa_g[4 * i + 3]); t1 = aread(wa_o[4 * i + 3]);
                a2 = fmaf(t0, hv.w, a2);     a3 = fmaf(t1, hv.w, a3);
            }
            // reduce across 4 slice-lanes (masks 1,2 -> DPP quad-perm)
            a0 += __shfl_xor(a0, 1); a0 += __shfl_xor(a0, 2);
            a1 += __shfl_xor(a1, 1); a1 += __shfl_xor(a1, 2);
            a2 += __shfl_xor(a2, 1); a2 += __shfl_xor(a2, 2);
            a3 += __shfl_xor(a3, 1); a3 += __shfl_xor(a3, 2);

            // xg (contains both biases) added once, after the reduce
            a0 += xg_s[k][0][j];
            a1 += xg_s[k][1][j];
            a2 += xg_s[k][2][j];
            a3 += xg_s[k][3][j];

            float gi = fsigmoid(a0);
            float gf = fsigmoid(a1);
            float gg = ftanh2(a2);
            float go = fsigmoid(a3);
            c_reg = gf * c_reg + gi * gg;     // identical in all 4 replicas
            float hv = go * ftanh2(c_reg);

            if (s == 0) h_p[p ^ 1][j >> 5][j & 31] = hv;
            __syncthreads();
        }
    }

    // ---- classifier head: final h in parity-0 buffer ----
    if (t < NCLS) {
        float acc = b_out[t];
        const float* wr = W_out + (size_t)t * HH;
        #pragma unroll
        for (int jj = 0; jj < HH; ++jj)
            acc = fmaf(wr[jj], h_p[0][jj >> 5][jj & 31], acc);
        out[(size_t)b * NCLS + t] = acc;
    }
}

extern "C" void kernel_launch(void* const* d_in, const int* in_sizes, int n_in,
                              void* d_out, int out_size, void* d_ws, size_t ws_size,
                              hipStream_t stream) {
    const float* x      = (const float*)d_in[0];
    const float* conv_w = (const float*)d_in[1];
    const float* conv_b = (const float*)d_in[2];
    const float* gamma  = (const float*)d_in[3];
    const float* beta   = (const float*)d_in[4];
    const float* rmean  = (const float*)d_in[5];
    const float* rvar   = (const float*)d_in[6];
    const float* W_ih   = (const float*)d_in[7];
    const float* W_hh   = (const float*)d_in[8];
    const float* b_ih   = (const float*)d_in[9];
    const float* b_hh   = (const float*)d_in[10];
    const float* W_out  = (const float*)d_in[11];
    const float* b_out  = (const float*)d_in[12];
    float* out = (float*)d_out;
    (void)d_ws; (void)ws_size; (void)in_sizes; (void)n_in; (void)out_size;

    lstm_seq_kernel<<<BB, 512, 0, stream>>>(x, conv_w, conv_b, gamma, beta,
                                            rmean, rvar, W_ih, W_hh, b_ih, b_hh,
                                            W_out, b_out, out);
}